// Round 6
// baseline (134.044 us; speedup 1.0000x reference)
//
#include <hip/hip_runtime.h>
#include <hip/hip_bf16.h>

// Block-causal GQA attention, T=2048 HQ=16 HKV=4 D=128, block 256.
// q_ranges/k_ranges deterministic: q block r attends k < (r+1)*256.
#define T_   2048
#define HQ_  16
#define HKV_ 4
#define D_   128
#define QBLK 64
#define NQB  (T_/QBLK)   // 32
#define KVBLK 32

typedef float f32x4 __attribute__((ext_vector_type(4)));
typedef __bf16 bf16x8 __attribute__((ext_vector_type(8)));
typedef unsigned short u16;
typedef unsigned short u16x8 __attribute__((ext_vector_type(8)));
typedef unsigned long long u64;
typedef unsigned u32;

__device__ __forceinline__ u16 f2bf(float f) {
  unsigned u = __builtin_bit_cast(unsigned, f);
  u += 0x7FFFu + ((u >> 16) & 1u);   // RNE bf16
  return (u16)(u >> 16);
}

// ---------------- prep (unchanged from r4 — passed) -------------------------
#define QK_BLOCKS 1280
__global__ __launch_bounds__(256) void prep_all(
    const float* __restrict__ q, const float* __restrict__ k,
    const float* __restrict__ v, const float* __restrict__ ct,
    const float* __restrict__ st,
    u16* __restrict__ qr, u16* __restrict__ kr, u16* __restrict__ vt)
{
  __shared__ __attribute__((aligned(16))) char Lv[32 * 144];
  const int tid = threadIdx.x;
  const int bid = blockIdx.x;
  if (bid < QK_BLOCKS) {
    const float scale = 0.08838834764831845f; // 1/sqrt(128)
    const int NQT = T_ * HQ_ * 8;
    int gid = bid * 256 + tid;
    if (gid < NQT) {
      int j0 = (gid & 7) * 8;
      int h  = (gid >> 3) & 15;
      int t  = gid >> 7;
      const float* base = q + ((size_t)t * HQ_ + h) * D_;
      const float* cb = ct + t * 64 + j0;
      const float* sb = st + t * 64 + j0;
      u16 lo[8], hi[8];
#pragma unroll
      for (int e = 0; e < 8; ++e) {
        float x1 = base[j0 + e], x2 = base[j0 + 64 + e];
        float c = cb[e], s = sb[e];
        lo[e] = f2bf((x1 * c - x2 * s) * scale);
        hi[e] = f2bf((x2 * c + x1 * s) * scale);
      }
      u16* orow = qr + ((size_t)h * T_ + t) * D_;
      *reinterpret_cast<u16x8*>(orow + j0)      = *reinterpret_cast<u16x8*>(lo);
      *reinterpret_cast<u16x8*>(orow + 64 + j0) = *reinterpret_cast<u16x8*>(hi);
    } else {
      int th = gid - NQT;
      int j0 = (th & 7) * 8;
      int hh = (th >> 3) & 3;
      int t  = th >> 5;
      const float* base = k + ((size_t)t * HKV_ + hh) * D_;
      const float* cb = ct + t * 64 + j0;
      const float* sb = st + t * 64 + j0;
      u16 lo[8], hi[8];
#pragma unroll
      for (int e = 0; e < 8; ++e) {
        float x1 = base[j0 + e], x2 = base[j0 + 64 + e];
        float c = cb[e], s = sb[e];
        lo[e] = f2bf(x1 * c - x2 * s);
        hi[e] = f2bf(x2 * c + x1 * s);
      }
      u16* orow = kr + ((size_t)hh * T_ + t) * D_;
      *reinterpret_cast<u16x8*>(orow + j0)      = *reinterpret_cast<u16x8*>(lo);
      *reinterpret_cast<u16x8*>(orow + 64 + j0) = *reinterpret_cast<u16x8*>(hi);
    }
  } else {
    int vbid = bid - QK_BLOCKS;
    int hh = vbid & 3;
    int t0 = ((vbid >> 2) & 31) * 64;
    int d0 = (vbid >> 7) * 32;
    {
      int r  = tid >> 2;
      int dg = tid & 3;
      const float* vrow = v + ((size_t)(t0 + r) * HKV_ + hh) * D_ + d0 + dg * 8;
      float4 f0 = *reinterpret_cast<const float4*>(vrow);
      float4 f1 = *reinterpret_cast<const float4*>(vrow + 4);
      float fv[8] = {f0.x, f0.y, f0.z, f0.w, f1.x, f1.y, f1.z, f1.w};
#pragma unroll
      for (int e = 0; e < 8; ++e)
        *reinterpret_cast<u16*>(Lv + (dg * 8 + e) * 144 + r * 2) = f2bf(fv[e]);
    }
    __syncthreads();
    {
      int dl = tid >> 3;
      int c0 = (tid & 7) * 16;
      u16x8 val = *reinterpret_cast<const u16x8*>(Lv + dl * 144 + c0);
      u16* orow = vt + ((size_t)(hh * D_ + d0 + dl)) * T_ + t0 + (c0 >> 1);
      *reinterpret_cast<u16x8*>(orow) = val;
    }
  }
}

// ---------------- flash attention ------------------------------------------
// WG = (q-block 64, head); 4 waves x 16 q-rows; KV tile 32, double-buffered,
// ONE barrier per tile, reg-prefetch staging. S^T = K*Q (stats lane-local at
// q=lane&15); O^T = V^T * P^T.
// LDS 40KB: K 2x8K | VT 2x8K (2 d-rows packed per 128B row) | P 4x2K
// -> 4 blocks/CU (16 waves/CU), __launch_bounds__(256,4) caps VGPR at 128.
__global__ __launch_bounds__(256, 4) void attn_fwd(
    const u16* __restrict__ qr, const u16* __restrict__ kr,
    const u16* __restrict__ vt, float* __restrict__ out)
{
  __shared__ __attribute__((aligned(16))) char lds[40960];

  const int tid  = threadIdx.x;
  const int lane = tid & 63;
  const int wv   = tid >> 6;
  char* Plds = lds + 32768 + wv * 2048;

  const int bid = blockIdx.x;
  const int f   = (bid ^ (bid >> 8)) & 1;
  const int x   = (bid >> 4) & 15;
  const int h   = ((bid >> 1) & 7) | (((bid >> 8) & 1) << 3);
  const int qb  = f ? (31 - x) : x;
  const int hkv = h >> 2;
  const int q0  = qb * QBLK + wv * 16;
  const int nt  = ((qb >> 2) + 1) * 8;      // 32-wide KV tiles

  const int lm = lane & 15;
  const int lh = lane >> 4;

  // Q fragments (B-operand): lane holds Q[q=lm][kb*32 + 8*lh + i]
  bf16x8 qf[4];
  {
    const u16* qrow = qr + ((size_t)h * T_ + q0 + lm) * D_;
#pragma unroll
    for (int kb = 0; kb < 4; ++kb)
      qf[kb] = *reinterpret_cast<const bf16x8*>(qrow + kb * 32 + lh * 8);
  }

  const u16* kbase = kr + (size_t)hkv * T_ * D_;  // [t][128]
  const u16* vbase = vt + (size_t)hkv * D_ * T_;  // [d][2048]

  // staging addresses (per thread, tile-invariant except kv0)
  const int ks_row  = tid >> 4;              // 0..15 (+16 for j=1)
  const int ks_colb = (tid & 15) * 16;       // byte col in 256B row
  const int vs_d    = tid >> 1;              // 0..127
  const int vs_half = tid & 1;               // which 16-t half

  bf16x8 ksta[2], vsta[2];
#pragma unroll
  for (int j = 0; j < 2; ++j) {   // prologue: tile 0 -> regs
    ksta[j] = *reinterpret_cast<const bf16x8*>(
        kbase + (size_t)(ks_row + j * 16) * D_ + (ks_colb >> 1));
    vsta[j] = *reinterpret_cast<const bf16x8*>(
        vbase + (size_t)vs_d * T_ + vs_half * 16 + j * 8);
  }

  f32x4 accO[8];
#pragma unroll
  for (int c = 0; c < 8; ++c) accO[c] = (f32x4){0.f, 0.f, 0.f, 0.f};
  float mrun = -1e30f, lrun = 0.f;

  for (int t = 0; t < nt; ++t) {
    char* Klds  = lds + (t & 1) * 8192;
    char* VTlds = lds + 16384 + (t & 1) * 8192;
    // ---- ds_write staged tile t into buf[t&1]; reads of this buf from
    // tile t-2 drained at barrier(t-1) ----
#pragma unroll
    for (int j = 0; j < 2; ++j) {
      int row = ks_row + j * 16;
      int off = row * 256 + ks_colb;
      *reinterpret_cast<bf16x8*>(Klds + (off ^ ((row & 7) << 4))) = ksta[j];
      int prow = vs_d >> 1;
      int colb = (vs_d & 1) * 64 + vs_half * 32 + j * 16;
      *reinterpret_cast<bf16x8*>(
          VTlds + prow * 128 + (colb ^ ((prow & 7) << 4))) = vsta[j];
    }
    // ---- prefetch tile t+1 -> regs (overlaps this tile's compute) ----
    if (t + 1 < nt) {
      const int kv1 = (t + 1) * KVBLK;
#pragma unroll
      for (int j = 0; j < 2; ++j) {
        ksta[j] = *reinterpret_cast<const bf16x8*>(
            kbase + (size_t)(kv1 + ks_row + j * 16) * D_ + (ks_colb >> 1));
        vsta[j] = *reinterpret_cast<const bf16x8*>(
            vbase + (size_t)vs_d * T_ + kv1 + vs_half * 16 + j * 8);
      }
    }
    __syncthreads();   // tile t visible

    // ---- QK^T: S^T[kk=16g+4lh+i][q=lm] ----
    f32x4 s[2];
#pragma unroll
    for (int g = 0; g < 2; ++g) s[g] = (f32x4){0.f, 0.f, 0.f, 0.f};
    __builtin_amdgcn_s_setprio(1);
#pragma unroll
    for (int kb = 0; kb < 4; ++kb) {
#pragma unroll
      for (int g = 0; g < 2; ++g) {
        int row = lm + 16 * g;
        bf16x8 kf = *reinterpret_cast<const bf16x8*>(
            Klds + ((row * 256 + kb * 64 + lh * 16) ^ ((row & 7) << 4)));
        s[g] = __builtin_amdgcn_mfma_f32_16x16x32_bf16(kf, qf[kb], s[g], 0, 0, 0);
      }
    }
    __builtin_amdgcn_s_setprio(0);

    // ---- online softmax (per q column = lm) ----
    float tmax = fmaxf(fmaxf(fmaxf(s[0][0], s[0][1]), fmaxf(s[0][2], s[0][3])),
                       fmaxf(fmaxf(s[1][0], s[1][1]), fmaxf(s[1][2], s[1][3])));
    tmax = fmaxf(tmax, __shfl_xor(tmax, 16));
    tmax = fmaxf(tmax, __shfl_xor(tmax, 32));
    float mnew  = fmaxf(mrun, tmax);
    float alpha = __expf(mrun - mnew);
    float psum = 0.f;
#pragma unroll
    for (int g = 0; g < 2; ++g) {
      float p0 = __expf(s[g][0] - mnew), p1 = __expf(s[g][1] - mnew);
      float p2 = __expf(s[g][2] - mnew), p3 = __expf(s[g][3] - mnew);
      psum += (p0 + p1) + (p2 + p3);
      u32 r01, r23;
      asm("v_cvt_pk_bf16_f32 %0, %1, %2" : "=v"(r01) : "v"(p0), "v"(p1));
      asm("v_cvt_pk_bf16_f32 %0, %1, %2" : "=v"(r23) : "v"(p2), "v"(p3));
      u64 w = (u64)r01 | ((u64)r23 << 32);
      *reinterpret_cast<u64*>(
          Plds + lm * 128 + ((g * 32 + lh * 8) ^ ((lm & 7) << 4))) = w;
    }
    psum += __shfl_xor(psum, 16);
    psum += __shfl_xor(psum, 32);
    lrun = lrun * alpha + psum;
    mrun = mnew;
#pragma unroll
    for (int c = 0; c < 8; ++c) {
      accO[c][0] *= alpha; accO[c][1] *= alpha;
      accO[c][2] *= alpha; accO[c][3] *= alpha;
    }

    // ---- PV: O^T += V^T * P^T  (B-frag: P^T[kk=8lh+i][q=lm]) ----
    bf16x8 pf = *reinterpret_cast<const bf16x8*>(
        Plds + lm * 128 + ((lh * 16) ^ ((lm & 7) << 4)));
    __builtin_amdgcn_s_setprio(1);
#pragma unroll
    for (int c = 0; c < 8; ++c) {
      int row  = c * 16 + lm;
      int prow = row >> 1;
      int colb = (row & 1) * 64 + lh * 16;
      bf16x8 vf = *reinterpret_cast<const bf16x8*>(
          VTlds + prow * 128 + (colb ^ ((prow & 7) << 4)));
      accO[c] = __builtin_amdgcn_mfma_f32_16x16x32_bf16(vf, pf, accO[c], 0, 0, 0);
    }
    __builtin_amdgcn_s_setprio(0);
  }

  // ---- epilogue: lane holds O^T[d=c*16+4lh+i][q=lm] ----
  float inv = 1.f / lrun;
  float* orow = out + ((size_t)(q0 + lm) * HQ_ + h) * D_ + lh * 4;
#pragma unroll
  for (int c = 0; c < 8; ++c) {
    f32x4 o;
    o[0] = accO[c][0] * inv; o[1] = accO[c][1] * inv;
    o[2] = accO[c][2] * inv; o[3] = accO[c][3] * inv;
    *reinterpret_cast<f32x4*>(orow + c * 16) = o;
  }
}

extern "C" void kernel_launch(void* const* d_in, const int* in_sizes, int n_in,
                              void* d_out, int out_size, void* d_ws, size_t ws_size,
                              hipStream_t stream) {
  const float* q  = (const float*)d_in[0];
  const float* k  = (const float*)d_in[1];
  const float* v  = (const float*)d_in[2];
  const float* ct = (const float*)d_in[3];
  const float* st = (const float*)d_in[4];

  u16* qr = (u16*)d_ws;                            // 8 MB  [h][t][128]
  u16* kr = qr + (size_t)T_ * HQ_ * D_;            // 2 MB  [hkv][t][128]
  u16* vt = kr + (size_t)T_ * HKV_ * D_;           // 2 MB  [hkv][d][t]
  float* out = (float*)d_out;

  prep_all<<<QK_BLOCKS + 512, 256, 0, stream>>>(q, k, v, ct, st, qr, kr, vt);
  attn_fwd<<<NQB * HQ_, 256, 0, stream>>>(qr, kr, vt, out);
}